// Round 10
// baseline (443.287 us; speedup 1.0000x reference)
//
#include <hip/hip_runtime.h>

#define BB 16
#define NN 4096
#define SS 1024
#define KK 32
#define MPTS (BB*SS*KK)      // 524288
#define EPSF 1e-5f
#define CANDCAP 1024
#define NARROW 48

// workspace layout (float offsets)
#define OFF_QP    0                       // B*S*4
#define OFF_P4    (OFF_QP + BB*SS*4)      // B*N*4
#define OFF_ST    (OFF_P4 + BB*NN*4)      // 512 floats zeroed each call
#define OFF_MOM   (OFF_ST)                // 27
#define OFF_S1SUM (OFF_ST+32)             // 64
#define OFF_S1SQ  (OFF_ST+96)             // 64
#define OFF_S2SUM (OFF_ST+160)            // 128
#define OFF_S2SQ  (OFF_ST+288)            // 128
#define OFF_XG    (OFF_ST+1280)           // 6*MPTS channel-major
#define OFF_MAXB  (OFF_XG + 6*MPTS)       // B*S*128
#define OFF_MINB  (OFF_MAXB + BB*SS*128)  // B*S*128
#define OFF_Y1U   (OFF_MINB + BB*SS*128)  // bf16 (ushort) POINT-major [MPTS][64]

typedef __bf16 bf16x8 __attribute__((ext_vector_type(8)));
typedef float f32x4 __attribute__((ext_vector_type(4)));
typedef unsigned int uintx4 __attribute__((ext_vector_type(4)));

__device__ __forceinline__ unsigned rne_bf16(float f){
  unsigned u = __float_as_uint(f);
  return (u + 0x7FFFu + ((u>>16)&1u)) >> 16;   // RNE f32->bf16 (finite, non-NaN)
}

__global__ __launch_bounds__(256) void prep_kernel(
    const float* __restrict__ xyz, const int* __restrict__ fps,
    float* __restrict__ out, float* __restrict__ ws)
{
  const int g = blockIdx.x*256 + threadIdx.x;
  if (g < BB*NN){
    const float* p = xyz + (size_t)g*3;
    float x=p[0], y=p[1], z=p[2];
    float x2 = __fadd_rn(__fadd_rn(__fmul_rn(x,x),__fmul_rn(y,y)),__fmul_rn(z,z));
    *reinterpret_cast<float4*>(ws + OFF_P4 + (size_t)g*4) = make_float4(x,y,z,x2);
  } else {
    int j = g - BB*NN;
    if (j < BB*SS){
      int b = j >> 10;
      int idx = fps[j];
      const float* p = xyz + ((size_t)b*NN + idx)*3;
      float x=p[0], y=p[1], z=p[2];
      out[(size_t)j*3+0]=x; out[(size_t)j*3+1]=y; out[(size_t)j*3+2]=z;
      float q2 = __fadd_rn(__fadd_rn(__fmul_rn(x,x),__fmul_rn(y,y)),__fmul_rn(z,z));
      *reinterpret_cast<float4*>(ws + OFF_QP + (size_t)j*4) = make_float4(x,y,z,q2);
    }
  }
}

// one block per query: exact 32-NN. Keys in registers; top-byte histogram
// (plain LDS atomics — measured cheaper than ballot-leader's ~64 VALU/iter);
// compact boundary-bin keys once, then narrow ON THE CAND LIST (<=1024,
// ping-pong) until <= NARROW; exact rank-select on packed (key<<32|idx).
__global__ __launch_bounds__(256) void knn_group_kernel(
    const float* __restrict__ pts, float* __restrict__ ws)
{
  __shared__ unsigned hist[256];
  __shared__ unsigned wsum[4];
  __shared__ unsigned long long candA[CANDCAP];
  __shared__ unsigned long long candB[CANDCAP];
  __shared__ int sel[KK];
  __shared__ unsigned sh_b, sh_kk, sh_m;
  __shared__ int sh_nlt;
  __shared__ unsigned sh_mcnt;

  const int bid = blockIdx.x;
  const int b = bid >> 10;
  const int tid = threadIdx.x;
  const int lane = tid & 63;
  const int wv = tid >> 6;

  const float4 q = *reinterpret_cast<const float4*>(ws + OFF_QP + (size_t)bid*4);
  const float qx=q.x, qy=q.y, qz=q.z, q2=q.w;
  const float4* pb = reinterpret_cast<const float4*>(ws + OFF_P4) + (size_t)b*NN;

  unsigned k[16];            // static-indexed only (all loops unrolled)
  #pragma unroll
  for (int j=0;j<16;j++){
    int n = tid + j*256;
    float4 P = pb[n];
    float dot = __fadd_rn(__fadd_rn(__fmul_rn(qx,P.x),__fmul_rn(qy,P.y)),__fmul_rn(qz,P.z));
    float d = __fsub_rn(__fadd_rn(q2, P.w), __fmul_rn(2.0f,dot));
    unsigned u = __float_as_uint(d);
    k[j] = u ^ (unsigned)(((int)u>>31) | (int)0x80000000);
  }

  // ---- L3 histogram over top byte (plain LDS atomics) ----
  hist[tid] = 0;
  if (tid==0){ sh_nlt = 0; sh_mcnt = 0; }
  __syncthreads();
  #pragma unroll
  for (int j=0;j<16;j++) atomicAdd(&hist[k[j]>>24], 1u);
  __syncthreads();
  {
    unsigned orig = hist[tid];
    unsigned v = orig;
    #pragma unroll
    for (int off=1; off<64; off<<=1){
      unsigned u = __shfl_up(v, (unsigned)off, 64);
      if (lane >= off) v += u;
    }
    if (lane==63) wsum[wv] = v;
    __syncthreads();
    unsigned add = 0;
    #pragma unroll
    for (int kq=0;kq<3;kq++) if (wv > kq) add += wsum[kq];
    unsigned cum = v + add;
    unsigned lower = cum - orig;
    if (cum >= (unsigned)KK && lower < (unsigned)KK){
      sh_b = (unsigned)tid; sh_kk = (unsigned)KK - lower; sh_m = orig;
    }
    __syncthreads();
  }
  int kk = (int)sh_kk;
  unsigned m3 = sh_m;
  unsigned prefix = sh_b << 24;
  unsigned maskhi = 0xFF000000u;
  int Lstart = 2;                         // next byte level for cand narrowing

  // ---- rare fallback: boundary bin too big for cand buffer -> one more
  //      full-key narrowing pass at byte2 ----
  if (m3 > CANDCAP){
    hist[tid]=0; __syncthreads();
    #pragma unroll
    for (int j=0;j<16;j++)
      if ((k[j] & maskhi) == prefix) atomicAdd(&hist[(k[j]>>16)&0xFFu], 1u);
    __syncthreads();
    unsigned orig = hist[tid], v = orig;
    #pragma unroll
    for (int off=1; off<64; off<<=1){
      unsigned u = __shfl_up(v, (unsigned)off, 64);
      if (lane >= off) v += u;
    }
    if (lane==63) wsum[wv] = v;
    __syncthreads();
    unsigned add = 0;
    #pragma unroll
    for (int kq=0;kq<3;kq++) if (wv > kq) add += wsum[kq];
    unsigned cum = v + add;
    unsigned lower = cum - orig;
    if (cum >= (unsigned)kk && lower < (unsigned)kk){
      sh_b = (unsigned)tid; sh_kk = (unsigned)kk - lower; sh_m = orig;
    }
    __syncthreads();
    prefix |= sh_b << 16;
    maskhi |= 0x00FF0000u;
    kk = (int)sh_kk;
    Lstart = 1;
  }

  // ---- fused compact: below-prefix -> sel, equal-prefix -> candA ----
  #pragma unroll
  for (int j=0;j<16;j++){
    unsigned mk = k[j] & maskhi;
    int n = tid + j*256;
    if (mk < prefix){ int p = atomicAdd(&sh_nlt,1); sel[p] = n; }
    else if (mk == prefix){
      unsigned p = atomicAdd(&sh_mcnt,1u);
      if (p < CANDCAP) candA[p] = ((unsigned long long)k[j]<<32) | (unsigned)n;
    }
  }
  __syncthreads();
  unsigned m = (sh_mcnt < CANDCAP) ? sh_mcnt : CANDCAP;

  // ---- narrow on the cand list (cheap: <=4 entries/thread/pass) ----
  unsigned long long* ca = candA;
  unsigned long long* cb = candB;
  for (int L = Lstart; L >= 0 && m > NARROW; --L){
    const int sh = 32 + L*8;
    hist[tid] = 0;
    __syncthreads();
    for (unsigned i=tid; i<m; i+=256)
      atomicAdd(&hist[(unsigned)(ca[i]>>sh)&0xFFu], 1u);
    __syncthreads();
    unsigned orig = hist[tid], v = orig;
    #pragma unroll
    for (int off=1; off<64; off<<=1){
      unsigned u = __shfl_up(v, (unsigned)off, 64);
      if (lane >= off) v += u;
    }
    if (lane==63) wsum[wv] = v;
    __syncthreads();
    unsigned add = 0;
    #pragma unroll
    for (int kq=0;kq<3;kq++) if (wv > kq) add += wsum[kq];
    unsigned cum = v + add;
    unsigned lower = cum - orig;
    if (cum >= (unsigned)kk && lower < (unsigned)kk){
      sh_b = (unsigned)tid; sh_kk = (unsigned)kk - lower;
    }
    if (tid==0) sh_mcnt = 0;
    __syncthreads();
    unsigned bl = sh_b;
    kk = (int)sh_kk;
    for (unsigned i=tid; i<m; i+=256){
      unsigned long long ci = ca[i];
      unsigned byte = (unsigned)(ci>>sh)&0xFFu;
      if (byte < bl){ int p = atomicAdd(&sh_nlt,1); sel[p] = (int)(ci & 0xFFFFFFFFu); }
      else if (byte == bl){ unsigned p = atomicAdd(&sh_mcnt,1u); cb[p] = ci; }
    }
    __syncthreads();
    m = sh_mcnt;
    unsigned long long* t = ca; ca = cb; cb = t;
  }

  // ---- exact rank among remaining cand: (key,idx) lexicographic ----
  const int base = sh_nlt;
  for (unsigned i=tid; i<m; i+=256){
    const unsigned long long ci = ca[i];
    unsigned r = 0;
    for (unsigned jj=0; jj<m; ++jj) r += (ca[jj] < ci) ? 1u : 0u;
    if (r < (unsigned)kk) sel[base + (int)r] = (int)(ci & 0xFFFFFFFFu);
  }
  __syncthreads();

  // ---- gather the 32 neighbors, write grouped input channel-major ----
  if (tid < KK){
    int n = sel[tid];
    float4 P = pb[n];
    float v6[6];
    v6[0] = P.x-qx; v6[1] = P.y-qy; v6[2] = P.z-qz;
    const float* pt = pts + ((size_t)b*NN + n)*3;
    v6[3] = pt[0]; v6[4] = pt[1]; v6[5] = pt[2];
    size_t pidx = (size_t)bid*KK + tid;
    float* xg = ws + OFF_XG;
    #pragma unroll
    for (int c=0;c<6;c++) xg[(size_t)c*MPTS + pidx] = v6[c];
  }
}

// layer-0 input moments computed from the stored grouped input (L3-resident):
// 27 moments x 8 slices; one global atomicAdd per block (216 total).
__global__ __launch_bounds__(256) void mom2_kernel(float* __restrict__ ws)
{
  static const signed char C1[27]={0,1,2,3,4,5, 0,0,0,0,0,0, 1,1,1,1,1, 2,2,2,2, 3,3,3, 4,4, 5};
  static const signed char C2[27]={-1,-1,-1,-1,-1,-1, 0,1,2,3,4,5, 1,2,3,4,5, 2,3,4,5, 3,4,5, 4,5, 5};
  const int mq = blockIdx.x >> 3;
  const int sl = blockIdx.x & 7;
  const float4* xa = reinterpret_cast<const float4*>(ws + OFF_XG + (size_t)C1[mq]*MPTS) + (size_t)sl*(MPTS/32);
  const int c2 = C2[mq];
  float s = 0.f;
  if (c2 < 0){
    for (int i=threadIdx.x; i<MPTS/32; i+=256){
      float4 a = xa[i];
      s += (a.x+a.y)+(a.z+a.w);
    }
  } else {
    const float4* xb = reinterpret_cast<const float4*>(ws + OFF_XG + (size_t)c2*MPTS) + (size_t)sl*(MPTS/32);
    for (int i=threadIdx.x; i<MPTS/32; i+=256){
      float4 a = xa[i]; float4 bq = xb[i];
      s = fmaf(a.x,bq.x,s); s = fmaf(a.y,bq.y,s);
      s = fmaf(a.z,bq.z,s); s = fmaf(a.w,bq.w,s);
    }
  }
  #pragma unroll
  for (int off=32; off>=1; off>>=1) s += __shfl_xor(s,off,64);
  __shared__ float r[4];
  const int lane = threadIdx.x & 63, wv = threadIdx.x >> 6;
  if (lane==0) r[wv]=s;
  __syncthreads();
  if (threadIdx.x==0) atomicAdd(&ws[OFF_MOM+mq], r[0]+r[1]+r[2]+r[3]);
}

// thread = point: finalize0 folded into staging (tid<64 computes sc0/sh0 from
// the 27 moments); recompute h0 per channel on the fly, accumulate y1 in two
// chunks of 32, store raw y1 as bf16 POINT-major [p][64].
__global__ __launch_bounds__(256) void l1_kernel(
    const float* __restrict__ w0g, const float* __restrict__ b0g,
    const float* __restrict__ g0, const float* __restrict__ t0,
    const float* __restrict__ w1g, const float* __restrict__ b1g,
    float* __restrict__ ws)
{
  __shared__ float sw0[64*8];    // w0[c][0..5] at c*8
  __shared__ float sw1T[4096];   // [c][o]
  __shared__ float sb0[64], ssc0[64], ssh0[64], sb1[64];
  const int tid = threadIdx.x;
  for (int i=tid;i<384;i+=256){ int o=i/6, c=i-o*6; sw0[o*8+c] = w0g[i]; }
  for (int i=tid;i<4096;i+=256){ int c=i>>6, o=i&63; sw1T[c*64+o] = w1g[o*64+c]; }
  if (tid<64){
    // finalize0: BN0 scale/shift from input moments
    const float* mom = ws + OFF_MOM;
    float w[6];
    #pragma unroll
    for (int c=0;c<6;c++) w[c] = w0g[tid*6+c];
    float bo = b0g[tid];
    float wS = 0.f;
    #pragma unroll
    for (int c=0;c<6;c++) wS += w[c]*mom[c];
    const float Mf = (float)MPTS;
    float mean = (wS + Mf*bo) / Mf;
    float qsum = 0.f;
    int mi = 6;
    #pragma unroll
    for (int c=0;c<6;c++){
      #pragma unroll
      for (int c2=c;c2<6;c2++){
        float f = (c==c2)?1.f:2.f;
        qsum += f * w[c]*w[c2]*mom[mi];
        mi++;
      }
    }
    float E2  = (qsum + 2.f*bo*wS + Mf*bo*bo) / Mf;
    float var = E2 - mean*mean;
    float sc  = g0[tid] / sqrtf(var + EPSF);
    ssc0[tid] = sc;
    ssh0[tid] = t0[tid] - mean*sc;
    sb0[tid] = bo; sb1[tid] = b1g[tid];
  }
  __syncthreads();

  const size_t p = (size_t)blockIdx.x*256 + tid;
  const float* xg = ws + OFF_XG;
  const float x0=xg[p],        x1=xg[MPTS+p],   x2=xg[2ul*MPTS+p];
  const float x3=xg[3ul*MPTS+p], x4=xg[4ul*MPTS+p], x5=xg[5ul*MPTS+p];
  unsigned short* y1 = (unsigned short*)(ws + OFF_Y1U);

  for (int ch=0; ch<2; ++ch){
    float a[32];
    #pragma unroll
    for (int j=0;j<32;j++) a[j] = sb1[ch*32+j];
    for (int c=0;c<64;c++){
      const float4 wa = *reinterpret_cast<const float4*>(&sw0[c*8]);
      const float2 wb = *reinterpret_cast<const float2*>(&sw0[c*8+4]);
      float y = sb0[c];
      y = fmaf(wa.x,x0,y); y = fmaf(wa.y,x1,y); y = fmaf(wa.z,x2,y);
      y = fmaf(wa.w,x3,y); y = fmaf(wb.x,x4,y); y = fmaf(wb.y,x5,y);
      const float h = fmaxf(fmaf(ssc0[c], y, ssh0[c]), 0.f);
      const float4* wr = reinterpret_cast<const float4*>(&sw1T[c*64 + ch*32]);
      #pragma unroll
      for (int qq=0;qq<8;qq++){
        float4 wvv = wr[qq];
        a[qq*4+0] = fmaf(wvv.x,h,a[qq*4+0]);
        a[qq*4+1] = fmaf(wvv.y,h,a[qq*4+1]);
        a[qq*4+2] = fmaf(wvv.z,h,a[qq*4+2]);
        a[qq*4+3] = fmaf(wvv.w,h,a[qq*4+3]);
      }
    }
    unsigned uu[16];
    #pragma unroll
    for (int j=0;j<16;j++)
      uu[j] = rne_bf16(a[2*j]) | (rne_bf16(a[2*j+1])<<16);
    uint4* dst = reinterpret_cast<uint4*>(y1 + p*64 + ch*32);
    #pragma unroll
    for (int qq=0;qq<4;qq++)
      dst[qq] = make_uint4(uu[qq*4+0],uu[qq*4+1],uu[qq*4+2],uu[qq*4+3]);
  }
}

// per-channel sum/sumsq of y1 (bf16, point-major)
__global__ __launch_bounds__(256) void stats1_kernel(float* __restrict__ ws)
{
  __shared__ float redS[64], redQ[64];
  const int tid = threadIdx.x;
  if (tid<64){ redS[tid]=0.f; redQ[tid]=0.f; }
  __syncthreads();
  const int lane = tid & 63;
  const int c0 = (lane & 15)*4;     // channels c0..c0+3
  const int prow = tid >> 4;        // 0..15
  const unsigned short* y1 = (const unsigned short*)(ws + OFF_Y1U);
  const int base = blockIdx.x * 2048;
  float sv0=0,sv1=0,sv2=0,sv3=0, sq0=0,sq1=0,sq2=0,sq3=0;
  for (int p = base + prow; p < base + 2048; p += 16){
    uint2 u = *reinterpret_cast<const uint2*>(y1 + (size_t)p*64 + c0);
    float v0 = __uint_as_float(u.x<<16);
    float v1 = __uint_as_float(u.x & 0xFFFF0000u);
    float v2 = __uint_as_float(u.y<<16);
    float v3 = __uint_as_float(u.y & 0xFFFF0000u);
    sv0+=v0; sv1+=v1; sv2+=v2; sv3+=v3;
    sq0=fmaf(v0,v0,sq0); sq1=fmaf(v1,v1,sq1); sq2=fmaf(v2,v2,sq2); sq3=fmaf(v3,v3,sq3);
  }
  sv0 += __shfl_xor(sv0,16,64); sv0 += __shfl_xor(sv0,32,64);
  sv1 += __shfl_xor(sv1,16,64); sv1 += __shfl_xor(sv1,32,64);
  sv2 += __shfl_xor(sv2,16,64); sv2 += __shfl_xor(sv2,32,64);
  sv3 += __shfl_xor(sv3,16,64); sv3 += __shfl_xor(sv3,32,64);
  sq0 += __shfl_xor(sq0,16,64); sq0 += __shfl_xor(sq0,32,64);
  sq1 += __shfl_xor(sq1,16,64); sq1 += __shfl_xor(sq1,32,64);
  sq2 += __shfl_xor(sq2,16,64); sq2 += __shfl_xor(sq2,32,64);
  sq3 += __shfl_xor(sq3,16,64); sq3 += __shfl_xor(sq3,32,64);
  if (lane < 16){
    atomicAdd(&redS[c0+0], sv0); atomicAdd(&redS[c0+1], sv1);
    atomicAdd(&redS[c0+2], sv2); atomicAdd(&redS[c0+3], sv3);
    atomicAdd(&redQ[c0+0], sq0); atomicAdd(&redQ[c0+1], sq1);
    atomicAdd(&redQ[c0+2], sq2); atomicAdd(&redQ[c0+3], sq3);
  }
  __syncthreads();
  if (tid < 64){
    atomicAdd(&ws[OFF_S1SUM+tid], redS[tid]);
    atomicAdd(&ws[OFF_S1SQ+tid],  redQ[tid]);
  }
}

// MFMA layer 2 with finalize1 folded into staging (tid<64 computes sc1/sh1).
// C[512K x 128] = relu(bn1(Y1))[512K x 64] * W2[64 x 128] + b2.
// A-frag: m=lane&15 (point), k=(lane>>4)*8+j; D: col=lane&15, row=(lane>>4)*4+r.
__global__ __launch_bounds__(256) void l2_mfma_kernel(
    const float* __restrict__ w2g, const float* __restrict__ b2g,
    const float* __restrict__ g1, const float* __restrict__ t1,
    float* __restrict__ ws)
{
  __shared__ __align__(16) unsigned short sB[8192]; // [nt][kt][lane][j]
  __shared__ float s1c[64], s1h[64];
  __shared__ float red[256];
  const int tid = threadIdx.x;
  for (int idx=tid; idx<8192; idx+=256){
    int nt = idx>>10, kt = (idx>>9)&1, l = (idx>>3)&63, j = idx&7;
    int kch = kt*32 + ((l>>4)<<3) + j;
    int o   = (nt<<4) + (l&15);
    sB[idx] = (unsigned short)rne_bf16(w2g[o*64+kch]);
  }
  if (tid<64){
    // finalize1: BN1 scale/shift from y1 stats
    const float Mf = (float)MPTS;
    float mean = ws[OFF_S1SUM+tid]/Mf;
    float var  = ws[OFF_S1SQ+tid]/Mf - mean*mean;
    float sc = g1[tid]/sqrtf(var+EPSF);
    s1c[tid]=sc; s1h[tid]=t1[tid]-mean*sc;
  }
  red[tid]=0.f;
  __syncthreads();

  const int lane = tid & 63;
  const int w    = tid >> 6;
  const int col  = lane & 15;
  const int kg   = lane >> 4;    // 0..3

  float scv[2][8], shv[2][8];
  #pragma unroll
  for (int kt=0;kt<2;kt++)
    #pragma unroll
    for (int j=0;j<8;j++){
      scv[kt][j] = s1c[kt*32 + kg*8 + j];
      shv[kt][j] = s1h[kt*32 + kg*8 + j];
    }
  float b2v[8];
  #pragma unroll
  for (int nt=0;nt<8;nt++) b2v[nt] = b2g[nt*16 + col];

  const unsigned short* y1 = (const unsigned short*)(ws + OFF_Y1U);
  float* maxb = ws + OFF_MAXB;
  float* minb = ws + OFF_MINB;

  float sumacc[8], sqacc[8];
  #pragma unroll
  for (int nt=0;nt<8;nt++){ sumacc[nt]=0.f; sqacc[nt]=0.f; }

  const int gbase = (blockIdx.x*4 + w)*4;
  for (int it=0; it<4; ++it){
    const int g = gbase + it;
    const size_t p0 = (size_t)g*32;
    bf16x8 aA[2][2];
    #pragma unroll
    for (int mh=0; mh<2; ++mh){
      const unsigned short* arow = y1 + (p0 + mh*16 + col)*64 + kg*8;
      #pragma unroll
      for (int kt=0; kt<2; ++kt){
        uintx4 ua = *reinterpret_cast<const uintx4*>(arow + kt*32);
        float h0 = fmaxf(fmaf(scv[kt][0], __uint_as_float(ua[0]<<16),          shv[kt][0]), 0.f);
        float h1 = fmaxf(fmaf(scv[kt][1], __uint_as_float(ua[0]&0xFFFF0000u), shv[kt][1]), 0.f);
        float h2 = fmaxf(fmaf(scv[kt][2], __uint_as_float(ua[1]<<16),          shv[kt][2]), 0.f);
        float h3 = fmaxf(fmaf(scv[kt][3], __uint_as_float(ua[1]&0xFFFF0000u), shv[kt][3]), 0.f);
        float h4 = fmaxf(fmaf(scv[kt][4], __uint_as_float(ua[2]<<16),          shv[kt][4]), 0.f);
        float h5 = fmaxf(fmaf(scv[kt][5], __uint_as_float(ua[2]&0xFFFF0000u), shv[kt][5]), 0.f);
        float h6 = fmaxf(fmaf(scv[kt][6], __uint_as_float(ua[3]<<16),          shv[kt][6]), 0.f);
        float h7 = fmaxf(fmaf(scv[kt][7], __uint_as_float(ua[3]&0xFFFF0000u), shv[kt][7]), 0.f);
        uintx4 pk;
        pk[0] = rne_bf16(h0) | (rne_bf16(h1)<<16);
        pk[1] = rne_bf16(h2) | (rne_bf16(h3)<<16);
        pk[2] = rne_bf16(h4) | (rne_bf16(h5)<<16);
        pk[3] = rne_bf16(h6) | (rne_bf16(h7)<<16);
        aA[mh][kt] = __builtin_bit_cast(bf16x8, pk);
      }
    }
    f32x4 acc[2][8];
    #pragma unroll
    for (int mh=0;mh<2;mh++)
      #pragma unroll
      for (int nt=0;nt<8;nt++){
        f32x4 z = {b2v[nt], b2v[nt], b2v[nt], b2v[nt]};
        acc[mh][nt] = z;
      }
    #pragma unroll
    for (int nt=0;nt<8;nt++){
      #pragma unroll
      for (int kt=0;kt<2;kt++){
        uintx4 bu = *reinterpret_cast<const uintx4*>(&sB[((nt*2+kt)*64 + lane)*8]);
        bf16x8 bv = __builtin_bit_cast(bf16x8, bu);
        acc[0][nt] = __builtin_amdgcn_mfma_f32_16x16x32_bf16(aA[0][kt], bv, acc[0][nt], 0,0,0);
        acc[1][nt] = __builtin_amdgcn_mfma_f32_16x16x32_bf16(aA[1][kt], bv, acc[1][nt], 0,0,0);
      }
    }
    #pragma unroll
    for (int nt=0;nt<8;nt++){
      f32x4 a0 = acc[0][nt], a1 = acc[1][nt];
      float mx = fmaxf(fmaxf(fmaxf(a0[0],a0[1]),fmaxf(a0[2],a0[3])),
                       fmaxf(fmaxf(a1[0],a1[1]),fmaxf(a1[2],a1[3])));
      float mn = fminf(fminf(fminf(a0[0],a0[1]),fminf(a0[2],a0[3])),
                       fminf(fminf(a1[0],a1[1]),fminf(a1[2],a1[3])));
      mx = fmaxf(mx, __shfl_xor(mx,16,64)); mx = fmaxf(mx, __shfl_xor(mx,32,64));
      mn = fminf(mn, __shfl_xor(mn,16,64)); mn = fminf(mn, __shfl_xor(mn,32,64));
      float s = ((a0[0]+a0[1])+(a0[2]+a0[3])) + ((a1[0]+a1[1])+(a1[2]+a1[3]));
      sumacc[nt] += s;
      float qv = 0.f;
      qv = fmaf(a0[0],a0[0],qv); qv = fmaf(a0[1],a0[1],qv);
      qv = fmaf(a0[2],a0[2],qv); qv = fmaf(a0[3],a0[3],qv);
      qv = fmaf(a1[0],a1[0],qv); qv = fmaf(a1[1],a1[1],qv);
      qv = fmaf(a1[2],a1[2],qv); qv = fmaf(a1[3],a1[3],qv);
      sqacc[nt] += qv;
      if (lane < 16){
        maxb[(size_t)g*128 + nt*16 + lane] = mx;
        minb[(size_t)g*128 + nt*16 + lane] = mn;
      }
    }
  }
  #pragma unroll
  for (int nt=0;nt<8;nt++){
    float s = sumacc[nt]; s += __shfl_xor(s,16,64); s += __shfl_xor(s,32,64);
    float qv = sqacc[nt]; qv += __shfl_xor(qv,16,64); qv += __shfl_xor(qv,32,64);
    if (lane < 16){
      atomicAdd(&red[nt*16+lane], s);
      atomicAdd(&red[128+nt*16+lane], qv);
    }
  }
  __syncthreads();
  atomicAdd(&ws[OFF_S2SUM + tid], red[tid]);
}

__global__ __launch_bounds__(256) void final_out_kernel(
    const float* __restrict__ g2, const float* __restrict__ t2,
    const float* __restrict__ ws, float* __restrict__ out)
{
  const int g = blockIdx.x*256 + threadIdx.x; // B*S*128 threads
  const int o = g & 127;
  const float Mf = (float)MPTS;
  float mean = ws[OFF_S2SUM+o] / Mf;
  float var  = ws[OFF_S2SQ+o] / Mf - mean*mean;
  float sc = g2[o] / sqrtf(var + EPSF);
  float sh = t2[o] - mean*sc;
  float v = (sc > 0.f) ? ws[OFF_MAXB+g] : ws[OFF_MINB+g];
  out[BB*SS*3 + g] = fmaxf(fmaf(sc, v, sh), 0.f);
}

extern "C" void kernel_launch(void* const* d_in, const int* in_sizes, int n_in,
                              void* d_out, int out_size, void* d_ws, size_t ws_size,
                              hipStream_t stream)
{
  const float* xyz = (const float*)d_in[0];
  const float* pts = (const float*)d_in[1];
  const int*   fps = (const int*)d_in[2];
  const float* w0  = (const float*)d_in[3];
  const float* b0  = (const float*)d_in[4];
  const float* g0  = (const float*)d_in[5];
  const float* t0  = (const float*)d_in[6];
  const float* w1  = (const float*)d_in[7];
  const float* b1  = (const float*)d_in[8];
  const float* g1  = (const float*)d_in[9];
  const float* t1  = (const float*)d_in[10];
  const float* w2  = (const float*)d_in[11];
  const float* b2  = (const float*)d_in[12];
  const float* g2  = (const float*)d_in[13];
  const float* t2  = (const float*)d_in[14];
  float* out = (float*)d_out;
  float* ws  = (float*)d_ws;

  hipMemsetAsync((void*)(ws + OFF_ST), 0, 512*sizeof(float), stream);
  prep_kernel<<<320,256,0,stream>>>(xyz, fps, out, ws);
  knn_group_kernel<<<BB*SS,256,0,stream>>>(pts, ws);
  mom2_kernel<<<27*8,256,0,stream>>>(ws);
  l1_kernel<<<MPTS/256,256,0,stream>>>(w0,b0,g0,t0,w1,b1,ws);
  stats1_kernel<<<256,256,0,stream>>>(ws);
  l2_mfma_kernel<<<1024,256,0,stream>>>(w2,b2,g1,t1,ws);
  final_out_kernel<<<(BB*SS*128)/256,256,0,stream>>>(g2,t2,ws,out);
}

// Round 11
// 346.692 us; speedup vs baseline: 1.2786x; 1.2786x over previous
//
#include <hip/hip_runtime.h>

#define BB 16
#define NN 4096
#define SS 1024
#define KK 32
#define MPTS (BB*SS*KK)      // 524288
#define EPSF 1e-5f
#define CANDCAP 512
#define NARROW 48

// workspace layout (float offsets)
#define OFF_QP    0                       // B*S*4
#define OFF_P4    (OFF_QP + BB*SS*4)      // B*N*4
#define OFF_ST    (OFF_P4 + BB*NN*4)      // 512 floats zeroed each call
#define OFF_MOM   (OFF_ST)                // 27
#define OFF_S1SUM (OFF_ST+32)             // 64
#define OFF_S1SQ  (OFF_ST+96)             // 64
#define OFF_S2SUM (OFF_ST+160)            // 128
#define OFF_S2SQ  (OFF_ST+288)            // 128
#define OFF_XG    (OFF_ST+1280)           // 6*MPTS channel-major
#define OFF_MAXB  (OFF_XG + 6*MPTS)       // B*S*128
#define OFF_MINB  (OFF_MAXB + BB*SS*128)  // B*S*128
#define OFF_Y1U   (OFF_MINB + BB*SS*128)  // bf16 (ushort) POINT-major [MPTS][64]

typedef __bf16 bf16x8 __attribute__((ext_vector_type(8)));
typedef float f32x4 __attribute__((ext_vector_type(4)));
typedef unsigned int uintx4 __attribute__((ext_vector_type(4)));

__device__ __forceinline__ unsigned rne_bf16(float f){
  unsigned u = __float_as_uint(f);
  return (u + 0x7FFFu + ((u>>16)&1u)) >> 16;   // RNE f32->bf16 (finite, non-NaN)
}

__global__ __launch_bounds__(256) void prep_kernel(
    const float* __restrict__ xyz, const int* __restrict__ fps,
    float* __restrict__ out, float* __restrict__ ws)
{
  const int g = blockIdx.x*256 + threadIdx.x;
  if (g < BB*NN){
    const float* p = xyz + (size_t)g*3;
    float x=p[0], y=p[1], z=p[2];
    float x2 = __fadd_rn(__fadd_rn(__fmul_rn(x,x),__fmul_rn(y,y)),__fmul_rn(z,z));
    *reinterpret_cast<float4*>(ws + OFF_P4 + (size_t)g*4) = make_float4(x,y,z,x2);
  } else {
    int j = g - BB*NN;
    if (j < BB*SS){
      int b = j >> 10;
      int idx = fps[j];
      const float* p = xyz + ((size_t)b*NN + idx)*3;
      float x=p[0], y=p[1], z=p[2];
      out[(size_t)j*3+0]=x; out[(size_t)j*3+1]=y; out[(size_t)j*3+2]=z;
      float q2 = __fadd_rn(__fadd_rn(__fmul_rn(x,x),__fmul_rn(y,y)),__fmul_rn(z,z));
      *reinterpret_cast<float4*>(ws + OFF_QP + (size_t)j*4) = make_float4(x,y,z,q2);
    }
  }
}

// one block per query: exact 32-NN, histogram-free.
// Binary search on orderable-key space: count(key < mid) via ballot+popc
// (no LDS histogram, no scans). Bracket shrinks until <= NARROW candidates;
// compact bracket, exact rank-select on packed (key<<32|idx).
__global__ __launch_bounds__(256) void knn_group_kernel(
    const float* __restrict__ pts, float* __restrict__ ws)
{
  __shared__ unsigned wcnt[2][4];
  __shared__ unsigned long long cand[CANDCAP];
  __shared__ int sel[KK];
  __shared__ int sh_nlt;
  __shared__ unsigned sh_mcnt;

  const int bid = blockIdx.x;
  const int b = bid >> 10;
  const int tid = threadIdx.x;
  const int lane = tid & 63;
  const int wv = tid >> 6;

  const float4 q = *reinterpret_cast<const float4*>(ws + OFF_QP + (size_t)bid*4);
  const float qx=q.x, qy=q.y, qz=q.z, q2=q.w;
  const float4* pb = reinterpret_cast<const float4*>(ws + OFF_P4) + (size_t)b*NN;

  unsigned k[16];            // static-indexed only (all loops unrolled)
  #pragma unroll
  for (int j=0;j<16;j++){
    int n = tid + j*256;
    float4 P = pb[n];
    float dot = __fadd_rn(__fadd_rn(__fmul_rn(qx,P.x),__fmul_rn(qy,P.y)),__fmul_rn(qz,P.z));
    float d = __fsub_rn(__fadd_rn(q2, P.w), __fmul_rn(2.0f,dot));
    unsigned u = __float_as_uint(d);
    k[j] = u ^ (unsigned)(((int)u>>31) | (int)0x80000000);
  }

  if (tid==0){ sh_nlt = 0; sh_mcnt = 0; }

  // invariant: count(key < lo) < KK <= count(key < hi)
  unsigned long long lo = 0, hi = 1ull<<32;
  unsigned clo = 0, chi = NN;
  int rounds = 0;
  while (chi - clo > NARROW && (hi - lo) > 1 && rounds < 28){
    const unsigned mid = (unsigned)((lo + hi) >> 1);
    unsigned cnt = 0;
    #pragma unroll
    for (int j=0;j<16;j++)
      cnt += (unsigned)__popcll(__ballot((int)(k[j] < mid)));
    if (lane==0) wcnt[rounds&1][wv] = cnt;
    __syncthreads();
    const unsigned c = wcnt[rounds&1][0]+wcnt[rounds&1][1]
                     + wcnt[rounds&1][2]+wcnt[rounds&1][3];
    if (c >= (unsigned)KK){ hi = mid; chi = c; } else { lo = mid; clo = c; }
    ++rounds;
  }

  // compact: below-bracket -> sel (arbitrary order; group is a set),
  // in-bracket -> cand as packed (key<<32|idx)
  const unsigned lo32 = (unsigned)lo;
  #pragma unroll
  for (int j=0;j<16;j++){
    int n = tid + j*256;
    if (k[j] < lo32){ int p = atomicAdd(&sh_nlt,1); sel[p] = n; }
    else if ((unsigned long long)k[j] < hi){
      unsigned p = atomicAdd(&sh_mcnt,1u);
      if (p < CANDCAP) cand[p] = ((unsigned long long)k[j]<<32) | (unsigned)n;
    }
  }
  __syncthreads();
  const int nlt = sh_nlt;
  const int kk = KK - nlt;
  const unsigned m = (sh_mcnt < CANDCAP) ? sh_mcnt : CANDCAP;
  // exact rank: (key,idx) lexicographic == packed u64 order (top_k tie rule)
  for (unsigned i=tid; i<m; i+=256){
    const unsigned long long ci = cand[i];
    unsigned r = 0;
    for (unsigned jj=0; jj<m; ++jj) r += (cand[jj] < ci) ? 1u : 0u;
    if (r < (unsigned)kk) sel[nlt + (int)r] = (int)(ci & 0xFFFFFFFFu);
  }
  __syncthreads();

  // gather the 32 neighbors, write grouped input channel-major
  if (tid < KK){
    int n = sel[tid];
    float4 P = pb[n];
    float v6[6];
    v6[0] = P.x-qx; v6[1] = P.y-qy; v6[2] = P.z-qz;
    const float* pt = pts + ((size_t)b*NN + n)*3;
    v6[3] = pt[0]; v6[4] = pt[1]; v6[5] = pt[2];
    size_t pidx = (size_t)bid*KK + tid;
    float* xg = ws + OFF_XG;
    #pragma unroll
    for (int c=0;c<6;c++) xg[(size_t)c*MPTS + pidx] = v6[c];
  }
}

// layer-0 input moments computed from the stored grouped input (L3-resident):
// 27 moments x 8 slices; one global atomicAdd per block (216 total).
__global__ __launch_bounds__(256) void mom2_kernel(float* __restrict__ ws)
{
  static const signed char C1[27]={0,1,2,3,4,5, 0,0,0,0,0,0, 1,1,1,1,1, 2,2,2,2, 3,3,3, 4,4, 5};
  static const signed char C2[27]={-1,-1,-1,-1,-1,-1, 0,1,2,3,4,5, 1,2,3,4,5, 2,3,4,5, 3,4,5, 4,5, 5};
  const int mq = blockIdx.x >> 3;
  const int sl = blockIdx.x & 7;
  const float4* xa = reinterpret_cast<const float4*>(ws + OFF_XG + (size_t)C1[mq]*MPTS) + (size_t)sl*(MPTS/32);
  const int c2 = C2[mq];
  float s = 0.f;
  if (c2 < 0){
    for (int i=threadIdx.x; i<MPTS/32; i+=256){
      float4 a = xa[i];
      s += (a.x+a.y)+(a.z+a.w);
    }
  } else {
    const float4* xb = reinterpret_cast<const float4*>(ws + OFF_XG + (size_t)c2*MPTS) + (size_t)sl*(MPTS/32);
    for (int i=threadIdx.x; i<MPTS/32; i+=256){
      float4 a = xa[i]; float4 bq = xb[i];
      s = fmaf(a.x,bq.x,s); s = fmaf(a.y,bq.y,s);
      s = fmaf(a.z,bq.z,s); s = fmaf(a.w,bq.w,s);
    }
  }
  #pragma unroll
  for (int off=32; off>=1; off>>=1) s += __shfl_xor(s,off,64);
  __shared__ float r[4];
  const int lane = threadIdx.x & 63, wv = threadIdx.x >> 6;
  if (lane==0) r[wv]=s;
  __syncthreads();
  if (threadIdx.x==0) atomicAdd(&ws[OFF_MOM+mq], r[0]+r[1]+r[2]+r[3]);
}

// thread = point: finalize0 folded into staging (tid<64 computes sc0/sh0 from
// the 27 moments); recompute h0 per channel on the fly, accumulate y1 in two
// chunks of 32, store raw y1 as bf16 POINT-major [p][64].
__global__ __launch_bounds__(256) void l1_kernel(
    const float* __restrict__ w0g, const float* __restrict__ b0g,
    const float* __restrict__ g0, const float* __restrict__ t0,
    const float* __restrict__ w1g, const float* __restrict__ b1g,
    float* __restrict__ ws)
{
  __shared__ float sw0[64*8];    // w0[c][0..5] at c*8
  __shared__ float sw1T[4096];   // [c][o]
  __shared__ float sb0[64], ssc0[64], ssh0[64], sb1[64];
  const int tid = threadIdx.x;
  for (int i=tid;i<384;i+=256){ int o=i/6, c=i-o*6; sw0[o*8+c] = w0g[i]; }
  for (int i=tid;i<4096;i+=256){ int c=i>>6, o=i&63; sw1T[c*64+o] = w1g[o*64+c]; }
  if (tid<64){
    // finalize0: BN0 scale/shift from input moments
    const float* mom = ws + OFF_MOM;
    float w[6];
    #pragma unroll
    for (int c=0;c<6;c++) w[c] = w0g[tid*6+c];
    float bo = b0g[tid];
    float wS = 0.f;
    #pragma unroll
    for (int c=0;c<6;c++) wS += w[c]*mom[c];
    const float Mf = (float)MPTS;
    float mean = (wS + Mf*bo) / Mf;
    float qsum = 0.f;
    int mi = 6;
    #pragma unroll
    for (int c=0;c<6;c++){
      #pragma unroll
      for (int c2=c;c2<6;c2++){
        float f = (c==c2)?1.f:2.f;
        qsum += f * w[c]*w[c2]*mom[mi];
        mi++;
      }
    }
    float E2  = (qsum + 2.f*bo*wS + Mf*bo*bo) / Mf;
    float var = E2 - mean*mean;
    float sc  = g0[tid] / sqrtf(var + EPSF);
    ssc0[tid] = sc;
    ssh0[tid] = t0[tid] - mean*sc;
    sb0[tid] = bo; sb1[tid] = b1g[tid];
  }
  __syncthreads();

  const size_t p = (size_t)blockIdx.x*256 + tid;
  const float* xg = ws + OFF_XG;
  const float x0=xg[p],        x1=xg[MPTS+p],   x2=xg[2ul*MPTS+p];
  const float x3=xg[3ul*MPTS+p], x4=xg[4ul*MPTS+p], x5=xg[5ul*MPTS+p];
  unsigned short* y1 = (unsigned short*)(ws + OFF_Y1U);

  for (int ch=0; ch<2; ++ch){
    float a[32];
    #pragma unroll
    for (int j=0;j<32;j++) a[j] = sb1[ch*32+j];
    for (int c=0;c<64;c++){
      const float4 wa = *reinterpret_cast<const float4*>(&sw0[c*8]);
      const float2 wb = *reinterpret_cast<const float2*>(&sw0[c*8+4]);
      float y = sb0[c];
      y = fmaf(wa.x,x0,y); y = fmaf(wa.y,x1,y); y = fmaf(wa.z,x2,y);
      y = fmaf(wa.w,x3,y); y = fmaf(wb.x,x4,y); y = fmaf(wb.y,x5,y);
      const float h = fmaxf(fmaf(ssc0[c], y, ssh0[c]), 0.f);
      const float4* wr = reinterpret_cast<const float4*>(&sw1T[c*64 + ch*32]);
      #pragma unroll
      for (int qq=0;qq<8;qq++){
        float4 wvv = wr[qq];
        a[qq*4+0] = fmaf(wvv.x,h,a[qq*4+0]);
        a[qq*4+1] = fmaf(wvv.y,h,a[qq*4+1]);
        a[qq*4+2] = fmaf(wvv.z,h,a[qq*4+2]);
        a[qq*4+3] = fmaf(wvv.w,h,a[qq*4+3]);
      }
    }
    unsigned uu[16];
    #pragma unroll
    for (int j=0;j<16;j++)
      uu[j] = rne_bf16(a[2*j]) | (rne_bf16(a[2*j+1])<<16);
    uint4* dst = reinterpret_cast<uint4*>(y1 + p*64 + ch*32);
    #pragma unroll
    for (int qq=0;qq<4;qq++)
      dst[qq] = make_uint4(uu[qq*4+0],uu[qq*4+1],uu[qq*4+2],uu[qq*4+3]);
  }
}

// per-channel sum/sumsq of y1 (bf16, point-major)
__global__ __launch_bounds__(256) void stats1_kernel(float* __restrict__ ws)
{
  __shared__ float redS[64], redQ[64];
  const int tid = threadIdx.x;
  if (tid<64){ redS[tid]=0.f; redQ[tid]=0.f; }
  __syncthreads();
  const int lane = tid & 63;
  const int c0 = (lane & 15)*4;     // channels c0..c0+3
  const int prow = tid >> 4;        // 0..15
  const unsigned short* y1 = (const unsigned short*)(ws + OFF_Y1U);
  const int base = blockIdx.x * 2048;
  float sv0=0,sv1=0,sv2=0,sv3=0, sq0=0,sq1=0,sq2=0,sq3=0;
  for (int p = base + prow; p < base + 2048; p += 16){
    uint2 u = *reinterpret_cast<const uint2*>(y1 + (size_t)p*64 + c0);
    float v0 = __uint_as_float(u.x<<16);
    float v1 = __uint_as_float(u.x & 0xFFFF0000u);
    float v2 = __uint_as_float(u.y<<16);
    float v3 = __uint_as_float(u.y & 0xFFFF0000u);
    sv0+=v0; sv1+=v1; sv2+=v2; sv3+=v3;
    sq0=fmaf(v0,v0,sq0); sq1=fmaf(v1,v1,sq1); sq2=fmaf(v2,v2,sq2); sq3=fmaf(v3,v3,sq3);
  }
  sv0 += __shfl_xor(sv0,16,64); sv0 += __shfl_xor(sv0,32,64);
  sv1 += __shfl_xor(sv1,16,64); sv1 += __shfl_xor(sv1,32,64);
  sv2 += __shfl_xor(sv2,16,64); sv2 += __shfl_xor(sv2,32,64);
  sv3 += __shfl_xor(sv3,16,64); sv3 += __shfl_xor(sv3,32,64);
  sq0 += __shfl_xor(sq0,16,64); sq0 += __shfl_xor(sq0,32,64);
  sq1 += __shfl_xor(sq1,16,64); sq1 += __shfl_xor(sq1,32,64);
  sq2 += __shfl_xor(sq2,16,64); sq2 += __shfl_xor(sq2,32,64);
  sq3 += __shfl_xor(sq3,16,64); sq3 += __shfl_xor(sq3,32,64);
  if (lane < 16){
    atomicAdd(&redS[c0+0], sv0); atomicAdd(&redS[c0+1], sv1);
    atomicAdd(&redS[c0+2], sv2); atomicAdd(&redS[c0+3], sv3);
    atomicAdd(&redQ[c0+0], sq0); atomicAdd(&redQ[c0+1], sq1);
    atomicAdd(&redQ[c0+2], sq2); atomicAdd(&redQ[c0+3], sq3);
  }
  __syncthreads();
  if (tid < 64){
    atomicAdd(&ws[OFF_S1SUM+tid], redS[tid]);
    atomicAdd(&ws[OFF_S1SQ+tid],  redQ[tid]);
  }
}

// MFMA layer 2 with finalize1 folded into staging (tid<64 computes sc1/sh1).
// C[512K x 128] = relu(bn1(Y1))[512K x 64] * W2[64 x 128] + b2.
// A-frag: m=lane&15 (point), k=(lane>>4)*8+j; D: col=lane&15, row=(lane>>4)*4+r.
__global__ __launch_bounds__(256) void l2_mfma_kernel(
    const float* __restrict__ w2g, const float* __restrict__ b2g,
    const float* __restrict__ g1, const float* __restrict__ t1,
    float* __restrict__ ws)
{
  __shared__ __align__(16) unsigned short sB[8192]; // [nt][kt][lane][j]
  __shared__ float s1c[64], s1h[64];
  __shared__ float red[256];
  const int tid = threadIdx.x;
  for (int idx=tid; idx<8192; idx+=256){
    int nt = idx>>10, kt = (idx>>9)&1, l = (idx>>3)&63, j = idx&7;
    int kch = kt*32 + ((l>>4)<<3) + j;
    int o   = (nt<<4) + (l&15);
    sB[idx] = (unsigned short)rne_bf16(w2g[o*64+kch]);
  }
  if (tid<64){
    // finalize1: BN1 scale/shift from y1 stats
    const float Mf = (float)MPTS;
    float mean = ws[OFF_S1SUM+tid]/Mf;
    float var  = ws[OFF_S1SQ+tid]/Mf - mean*mean;
    float sc = g1[tid]/sqrtf(var+EPSF);
    s1c[tid]=sc; s1h[tid]=t1[tid]-mean*sc;
  }
  red[tid]=0.f;
  __syncthreads();

  const int lane = tid & 63;
  const int w    = tid >> 6;
  const int col  = lane & 15;
  const int kg   = lane >> 4;    // 0..3

  float scv[2][8], shv[2][8];
  #pragma unroll
  for (int kt=0;kt<2;kt++)
    #pragma unroll
    for (int j=0;j<8;j++){
      scv[kt][j] = s1c[kt*32 + kg*8 + j];
      shv[kt][j] = s1h[kt*32 + kg*8 + j];
    }
  float b2v[8];
  #pragma unroll
  for (int nt=0;nt<8;nt++) b2v[nt] = b2g[nt*16 + col];

  const unsigned short* y1 = (const unsigned short*)(ws + OFF_Y1U);
  float* maxb = ws + OFF_MAXB;
  float* minb = ws + OFF_MINB;

  float sumacc[8], sqacc[8];
  #pragma unroll
  for (int nt=0;nt<8;nt++){ sumacc[nt]=0.f; sqacc[nt]=0.f; }

  const int gbase = (blockIdx.x*4 + w)*4;
  for (int it=0; it<4; ++it){
    const int g = gbase + it;
    const size_t p0 = (size_t)g*32;
    bf16x8 aA[2][2];
    #pragma unroll
    for (int mh=0; mh<2; ++mh){
      const unsigned short* arow = y1 + (p0 + mh*16 + col)*64 + kg*8;
      #pragma unroll
      for (int kt=0; kt<2; ++kt){
        uintx4 ua = *reinterpret_cast<const uintx4*>(arow + kt*32);
        float h0 = fmaxf(fmaf(scv[kt][0], __uint_as_float(ua[0]<<16),          shv[kt][0]), 0.f);
        float h1 = fmaxf(fmaf(scv[kt][1], __uint_as_float(ua[0]&0xFFFF0000u), shv[kt][1]), 0.f);
        float h2 = fmaxf(fmaf(scv[kt][2], __uint_as_float(ua[1]<<16),          shv[kt][2]), 0.f);
        float h3 = fmaxf(fmaf(scv[kt][3], __uint_as_float(ua[1]&0xFFFF0000u), shv[kt][3]), 0.f);
        float h4 = fmaxf(fmaf(scv[kt][4], __uint_as_float(ua[2]<<16),          shv[kt][4]), 0.f);
        float h5 = fmaxf(fmaf(scv[kt][5], __uint_as_float(ua[2]&0xFFFF0000u), shv[kt][5]), 0.f);
        float h6 = fmaxf(fmaf(scv[kt][6], __uint_as_float(ua[3]<<16),          shv[kt][6]), 0.f);
        float h7 = fmaxf(fmaf(scv[kt][7], __uint_as_float(ua[3]&0xFFFF0000u), shv[kt][7]), 0.f);
        uintx4 pk;
        pk[0] = rne_bf16(h0) | (rne_bf16(h1)<<16);
        pk[1] = rne_bf16(h2) | (rne_bf16(h3)<<16);
        pk[2] = rne_bf16(h4) | (rne_bf16(h5)<<16);
        pk[3] = rne_bf16(h6) | (rne_bf16(h7)<<16);
        aA[mh][kt] = __builtin_bit_cast(bf16x8, pk);
      }
    }
    f32x4 acc[2][8];
    #pragma unroll
    for (int mh=0;mh<2;mh++)
      #pragma unroll
      for (int nt=0;nt<8;nt++){
        f32x4 z = {b2v[nt], b2v[nt], b2v[nt], b2v[nt]};
        acc[mh][nt] = z;
      }
    #pragma unroll
    for (int nt=0;nt<8;nt++){
      #pragma unroll
      for (int kt=0;kt<2;kt++){
        uintx4 bu = *reinterpret_cast<const uintx4*>(&sB[((nt*2+kt)*64 + lane)*8]);
        bf16x8 bv = __builtin_bit_cast(bf16x8, bu);
        acc[0][nt] = __builtin_amdgcn_mfma_f32_16x16x32_bf16(aA[0][kt], bv, acc[0][nt], 0,0,0);
        acc[1][nt] = __builtin_amdgcn_mfma_f32_16x16x32_bf16(aA[1][kt], bv, acc[1][nt], 0,0,0);
      }
    }
    #pragma unroll
    for (int nt=0;nt<8;nt++){
      f32x4 a0 = acc[0][nt], a1 = acc[1][nt];
      float mx = fmaxf(fmaxf(fmaxf(a0[0],a0[1]),fmaxf(a0[2],a0[3])),
                       fmaxf(fmaxf(a1[0],a1[1]),fmaxf(a1[2],a1[3])));
      float mn = fminf(fminf(fminf(a0[0],a0[1]),fminf(a0[2],a0[3])),
                       fminf(fminf(a1[0],a1[1]),fminf(a1[2],a1[3])));
      mx = fmaxf(mx, __shfl_xor(mx,16,64)); mx = fmaxf(mx, __shfl_xor(mx,32,64));
      mn = fminf(mn, __shfl_xor(mn,16,64)); mn = fminf(mn, __shfl_xor(mn,32,64));
      float s = ((a0[0]+a0[1])+(a0[2]+a0[3])) + ((a1[0]+a1[1])+(a1[2]+a1[3]));
      sumacc[nt] += s;
      float qv = 0.f;
      qv = fmaf(a0[0],a0[0],qv); qv = fmaf(a0[1],a0[1],qv);
      qv = fmaf(a0[2],a0[2],qv); qv = fmaf(a0[3],a0[3],qv);
      qv = fmaf(a1[0],a1[0],qv); qv = fmaf(a1[1],a1[1],qv);
      qv = fmaf(a1[2],a1[2],qv); qv = fmaf(a1[3],a1[3],qv);
      sqacc[nt] += qv;
      if (lane < 16){
        maxb[(size_t)g*128 + nt*16 + lane] = mx;
        minb[(size_t)g*128 + nt*16 + lane] = mn;
      }
    }
  }
  #pragma unroll
  for (int nt=0;nt<8;nt++){
    float s = sumacc[nt]; s += __shfl_xor(s,16,64); s += __shfl_xor(s,32,64);
    float qv = sqacc[nt]; qv += __shfl_xor(qv,16,64); qv += __shfl_xor(qv,32,64);
    if (lane < 16){
      atomicAdd(&red[nt*16+lane], s);
      atomicAdd(&red[128+nt*16+lane], qv);
    }
  }
  __syncthreads();
  atomicAdd(&ws[OFF_S2SUM + tid], red[tid]);
}

__global__ __launch_bounds__(256) void final_out_kernel(
    const float* __restrict__ g2, const float* __restrict__ t2,
    const float* __restrict__ ws, float* __restrict__ out)
{
  const int g = blockIdx.x*256 + threadIdx.x; // B*S*128 threads
  const int o = g & 127;
  const float Mf = (float)MPTS;
  float mean = ws[OFF_S2SUM+o] / Mf;
  float var  = ws[OFF_S2SQ+o] / Mf - mean*mean;
  float sc = g2[o] / sqrtf(var + EPSF);
  float sh = t2[o] - mean*sc;
  float v = (sc > 0.f) ? ws[OFF_MAXB+g] : ws[OFF_MINB+g];
  out[BB*SS*3 + g] = fmaxf(fmaf(sc, v, sh), 0.f);
}

extern "C" void kernel_launch(void* const* d_in, const int* in_sizes, int n_in,
                              void* d_out, int out_size, void* d_ws, size_t ws_size,
                              hipStream_t stream)
{
  const float* xyz = (const float*)d_in[0];
  const float* pts = (const float*)d_in[1];
  const int*   fps = (const int*)d_in[2];
  const float* w0  = (const float*)d_in[3];
  const float* b0  = (const float*)d_in[4];
  const float* g0  = (const float*)d_in[5];
  const float* t0  = (const float*)d_in[6];
  const float* w1  = (const float*)d_in[7];
  const float* b1  = (const float*)d_in[8];
  const float* g1  = (const float*)d_in[9];
  const float* t1  = (const float*)d_in[10];
  const float* w2  = (const float*)d_in[11];
  const float* b2  = (const float*)d_in[12];
  const float* g2  = (const float*)d_in[13];
  const float* t2  = (const float*)d_in[14];
  float* out = (float*)d_out;
  float* ws  = (float*)d_ws;

  hipMemsetAsync((void*)(ws + OFF_ST), 0, 512*sizeof(float), stream);
  prep_kernel<<<320,256,0,stream>>>(xyz, fps, out, ws);
  knn_group_kernel<<<BB*SS,256,0,stream>>>(pts, ws);
  mom2_kernel<<<27*8,256,0,stream>>>(ws);
  l1_kernel<<<MPTS/256,256,0,stream>>>(w0,b0,g0,t0,w1,b1,ws);
  stats1_kernel<<<256,256,0,stream>>>(ws);
  l2_mfma_kernel<<<1024,256,0,stream>>>(w2,b2,g1,t1,ws);
  final_out_kernel<<<(BB*SS*128)/256,256,0,stream>>>(g2,t2,ws,out);
}

// Round 12
// 245.497 us; speedup vs baseline: 1.8057x; 1.4122x over previous
//
#include <hip/hip_runtime.h>

#define BB 16
#define NN 4096
#define SS 1024
#define KK 32
#define MPTS (BB*SS*KK)      // 524288
#define EPSF 1e-5f
#define CANDCAP 512
#define NARROW 48

// workspace layout (float offsets)
#define OFF_QP    0                       // B*S*4
#define OFF_P4    (OFF_QP + BB*SS*4)      // B*N*4
#define OFF_ST    (OFF_P4 + BB*NN*4)      // 512 floats zeroed each call
#define OFF_MOM   (OFF_ST)                // 27
#define OFF_S1SUM (OFF_ST+32)             // 64
#define OFF_S1SQ  (OFF_ST+96)             // 64
#define OFF_S2SUM (OFF_ST+160)            // 128
#define OFF_S2SQ  (OFF_ST+288)            // 128
#define OFF_WF0   (OFF_ST+512)            // folded l0 coefs [64][8]
#define OFF_XG    (OFF_ST+1280)           // 6*MPTS channel-major
#define OFF_MAXB  (OFF_XG + 6*MPTS)       // B*S*128
#define OFF_MINB  (OFF_MAXB + BB*SS*128)  // B*S*128
#define OFF_Y1U   (OFF_MINB + BB*SS*128)  // bf16 (ushort) POINT-major [MPTS][64]

typedef __bf16 bf16x8 __attribute__((ext_vector_type(8)));
typedef float f32x4 __attribute__((ext_vector_type(4)));
typedef unsigned int uintx4 __attribute__((ext_vector_type(4)));

__device__ __forceinline__ unsigned rne_bf16(float f){
  unsigned u = __float_as_uint(f);
  return (u + 0x7FFFu + ((u>>16)&1u)) >> 16;   // RNE f32->bf16 (finite, non-NaN)
}

__global__ __launch_bounds__(256) void prep_kernel(
    const float* __restrict__ xyz, const int* __restrict__ fps,
    float* __restrict__ out, float* __restrict__ ws)
{
  const int g = blockIdx.x*256 + threadIdx.x;
  if (g < BB*NN){
    const float* p = xyz + (size_t)g*3;
    float x=p[0], y=p[1], z=p[2];
    float x2 = __fadd_rn(__fadd_rn(__fmul_rn(x,x),__fmul_rn(y,y)),__fmul_rn(z,z));
    *reinterpret_cast<float4*>(ws + OFF_P4 + (size_t)g*4) = make_float4(x,y,z,x2);
  } else {
    int j = g - BB*NN;
    if (j < BB*SS){
      int b = j >> 10;
      int idx = fps[j];
      const float* p = xyz + ((size_t)b*NN + idx)*3;
      float x=p[0], y=p[1], z=p[2];
      out[(size_t)j*3+0]=x; out[(size_t)j*3+1]=y; out[(size_t)j*3+2]=z;
      float q2 = __fadd_rn(__fadd_rn(__fmul_rn(x,x),__fmul_rn(y,y)),__fmul_rn(z,z));
      *reinterpret_cast<float4*>(ws + OFF_QP + (size_t)j*4) = make_float4(x,y,z,q2);
    }
  }
}

// one block per query: exact 32-NN, histogram-free (binary search on key
// space; count via ballot+popc). Compact bracket, exact rank-select.
__global__ __launch_bounds__(256) void knn_group_kernel(
    const float* __restrict__ pts, float* __restrict__ ws)
{
  __shared__ unsigned wcnt[2][4];
  __shared__ unsigned long long cand[CANDCAP];
  __shared__ int sel[KK];
  __shared__ int sh_nlt;
  __shared__ unsigned sh_mcnt;

  const int bid = blockIdx.x;
  const int b = bid >> 10;
  const int tid = threadIdx.x;
  const int lane = tid & 63;
  const int wv = tid >> 6;

  const float4 q = *reinterpret_cast<const float4*>(ws + OFF_QP + (size_t)bid*4);
  const float qx=q.x, qy=q.y, qz=q.z, q2=q.w;
  const float4* pb = reinterpret_cast<const float4*>(ws + OFF_P4) + (size_t)b*NN;

  unsigned k[16];            // static-indexed only (all loops unrolled)
  #pragma unroll
  for (int j=0;j<16;j++){
    int n = tid + j*256;
    float4 P = pb[n];
    float dot = __fadd_rn(__fadd_rn(__fmul_rn(qx,P.x),__fmul_rn(qy,P.y)),__fmul_rn(qz,P.z));
    float d = __fsub_rn(__fadd_rn(q2, P.w), __fmul_rn(2.0f,dot));
    unsigned u = __float_as_uint(d);
    k[j] = u ^ (unsigned)(((int)u>>31) | (int)0x80000000);
  }

  if (tid==0){ sh_nlt = 0; sh_mcnt = 0; }

  // invariant: count(key < lo) < KK <= count(key < hi)
  unsigned long long lo = 0, hi = 1ull<<32;
  unsigned clo = 0, chi = NN;
  int rounds = 0;
  while (chi - clo > NARROW && (hi - lo) > 1 && rounds < 28){
    const unsigned mid = (unsigned)((lo + hi) >> 1);
    unsigned cnt = 0;
    #pragma unroll
    for (int j=0;j<16;j++)
      cnt += (unsigned)__popcll(__ballot((int)(k[j] < mid)));
    if (lane==0) wcnt[rounds&1][wv] = cnt;
    __syncthreads();
    const unsigned c = wcnt[rounds&1][0]+wcnt[rounds&1][1]
                     + wcnt[rounds&1][2]+wcnt[rounds&1][3];
    if (c >= (unsigned)KK){ hi = mid; chi = c; } else { lo = mid; clo = c; }
    ++rounds;
  }

  const unsigned lo32 = (unsigned)lo;
  #pragma unroll
  for (int j=0;j<16;j++){
    int n = tid + j*256;
    if (k[j] < lo32){ int p = atomicAdd(&sh_nlt,1); sel[p] = n; }
    else if ((unsigned long long)k[j] < hi){
      unsigned p = atomicAdd(&sh_mcnt,1u);
      if (p < CANDCAP) cand[p] = ((unsigned long long)k[j]<<32) | (unsigned)n;
    }
  }
  __syncthreads();
  const int nlt = sh_nlt;
  const int kk = KK - nlt;
  const unsigned m = (sh_mcnt < CANDCAP) ? sh_mcnt : CANDCAP;
  for (unsigned i=tid; i<m; i+=256){
    const unsigned long long ci = cand[i];
    unsigned r = 0;
    for (unsigned jj=0; jj<m; ++jj) r += (cand[jj] < ci) ? 1u : 0u;
    if (r < (unsigned)kk) sel[nlt + (int)r] = (int)(ci & 0xFFFFFFFFu);
  }
  __syncthreads();

  if (tid < KK){
    int n = sel[tid];
    float4 P = pb[n];
    float v6[6];
    v6[0] = P.x-qx; v6[1] = P.y-qy; v6[2] = P.z-qz;
    const float* pt = pts + ((size_t)b*NN + n)*3;
    v6[3] = pt[0]; v6[4] = pt[1]; v6[5] = pt[2];
    size_t pidx = (size_t)bid*KK + tid;
    float* xg = ws + OFF_XG;
    #pragma unroll
    for (int c=0;c<6;c++) xg[(size_t)c*MPTS + pidx] = v6[c];
  }
}

// layer-0 input moments from the stored grouped input (L3-resident)
__global__ __launch_bounds__(256) void mom2_kernel(float* __restrict__ ws)
{
  static const signed char C1[27]={0,1,2,3,4,5, 0,0,0,0,0,0, 1,1,1,1,1, 2,2,2,2, 3,3,3, 4,4, 5};
  static const signed char C2[27]={-1,-1,-1,-1,-1,-1, 0,1,2,3,4,5, 1,2,3,4,5, 2,3,4,5, 3,4,5, 4,5, 5};
  const int mq = blockIdx.x >> 3;
  const int sl = blockIdx.x & 7;
  const float4* xa = reinterpret_cast<const float4*>(ws + OFF_XG + (size_t)C1[mq]*MPTS) + (size_t)sl*(MPTS/32);
  const int c2 = C2[mq];
  float s = 0.f;
  if (c2 < 0){
    for (int i=threadIdx.x; i<MPTS/32; i+=256){
      float4 a = xa[i];
      s += (a.x+a.y)+(a.z+a.w);
    }
  } else {
    const float4* xb = reinterpret_cast<const float4*>(ws + OFF_XG + (size_t)c2*MPTS) + (size_t)sl*(MPTS/32);
    for (int i=threadIdx.x; i<MPTS/32; i+=256){
      float4 a = xa[i]; float4 bq = xb[i];
      s = fmaf(a.x,bq.x,s); s = fmaf(a.y,bq.y,s);
      s = fmaf(a.z,bq.z,s); s = fmaf(a.w,bq.w,s);
    }
  }
  #pragma unroll
  for (int off=32; off>=1; off>>=1) s += __shfl_xor(s,off,64);
  __shared__ float r[4];
  const int lane = threadIdx.x & 63, wv = threadIdx.x >> 6;
  if (lane==0) r[wv]=s;
  __syncthreads();
  if (threadIdx.x==0) atomicAdd(&ws[OFF_MOM+mq], r[0]+r[1]+r[2]+r[3]);
}

// BN0 scale/shift from moments, folded into h0 coefs:
// h0 = relu((sc*w0)·x + (sc*b0 + sh)) -> wf0[c][0..5]=sc*w0, [6]=sc*b0+sh
__global__ void finalize0b_kernel(const float* __restrict__ w0, const float* __restrict__ b0,
                                  const float* __restrict__ g0, const float* __restrict__ t0,
                                  float* __restrict__ ws)
{
  int o = threadIdx.x; // 64 threads
  const float* mom = ws + OFF_MOM;
  float w[6];
  #pragma unroll
  for (int c=0;c<6;c++) w[c] = w0[o*6+c];
  float bo = b0[o];
  float wS = 0.f;
  #pragma unroll
  for (int c=0;c<6;c++) wS += w[c]*mom[c];
  const float Mf = (float)MPTS;
  float mean = (wS + Mf*bo) / Mf;
  float qsum = 0.f;
  int mi = 6;
  #pragma unroll
  for (int c=0;c<6;c++){
    #pragma unroll
    for (int c2=c;c2<6;c2++){
      float f = (c==c2)?1.f:2.f;
      qsum += f * w[c]*w[c2]*mom[mi];
      mi++;
    }
  }
  float E2  = (qsum + 2.f*bo*wS + Mf*bo*bo) / Mf;
  float var = E2 - mean*mean;
  float sc  = g0[o] / sqrtf(var + EPSF);
  float sh  = t0[o] - mean*sc;
  float* wf = ws + OFF_WF0 + o*8;
  #pragma unroll
  for (int c=0;c<6;c++) wf[c] = sc*w[c];
  wf[6] = sc*bo + sh;
  wf[7] = 0.f;
}

// MFMA layer 1: Y1[512K x 64] = H0[512K x 64(only 6 eff)]... computed as
// D[o][p] = W1[o][c] * h0[c][p] per 16-point group. A = W1 (LDS, frag order),
// B = h0 computed in-register from folded coefs (c = kt*32+kg*8+j per lane).
// D: row=o=mt*16+kg*4+r (4 consecutive o per lane -> coalesced uint2 store),
// col=p. BN1 stats (sum/sumsq of raw y1) accumulated in-register and reduced
// here -- stats1 kernel eliminated.
__global__ __launch_bounds__(256) void l1_mfma_kernel(
    const float* __restrict__ w1g, const float* __restrict__ b1g,
    float* __restrict__ ws)
{
  __shared__ __align__(16) unsigned short sA1[4096]; // [mt*2+kt][lane][j]
  __shared__ float red[128];
  const int tid = threadIdx.x;
  const int lane = tid & 63;
  const int wv = tid >> 6;
  const int col = lane & 15;
  const int kg = lane >> 4;

  for (int idx=tid; idx<4096; idx+=256){
    int frag = idx>>9, l = (idx>>3)&63, j = idx&7;
    int mt = frag>>1, kt = frag&1;
    int o = mt*16 + (l&15);
    int c = kt*32 + ((l>>4)<<3) + j;
    sA1[idx] = (unsigned short)rne_bf16(w1g[o*64+c]);
  }
  if (tid<128) red[tid]=0.f;
  __syncthreads();

  // folded h0 coefs for this lane's 16 channels (c = kt*32 + kg*8 + j)
  const float* wf = ws + OFF_WF0;
  float cw0[2][8], cw1[2][8], cw2[2][8], cw3[2][8], cw4[2][8], cw5[2][8], cb[2][8];
  #pragma unroll
  for (int kt=0; kt<2; ++kt){
    #pragma unroll
    for (int j=0;j<8;j++){
      int c = kt*32 + kg*8 + j;
      float4 a4 = *reinterpret_cast<const float4*>(wf + c*8);
      float4 b4 = *reinterpret_cast<const float4*>(wf + c*8 + 4);
      cw0[kt][j]=a4.x; cw1[kt][j]=a4.y; cw2[kt][j]=a4.z; cw3[kt][j]=a4.w;
      cw4[kt][j]=b4.x; cw5[kt][j]=b4.y; cb[kt][j]=b4.z;
    }
  }
  float b1v[4][4];
  #pragma unroll
  for (int mt=0;mt<4;mt++)
    #pragma unroll
    for (int r=0;r<4;r++) b1v[mt][r] = b1g[mt*16 + kg*4 + r];

  float s1s[4][4], s1q[4][4];
  #pragma unroll
  for (int mt=0;mt<4;mt++)
    #pragma unroll
    for (int r=0;r<4;r++){ s1s[mt][r]=0.f; s1q[mt][r]=0.f; }

  const float* xg = ws + OFF_XG;
  unsigned short* y1 = (unsigned short*)(ws + OFF_Y1U);
  const int pbase = (blockIdx.x*4 + wv)*256;

  for (int it=0; it<16; ++it){
    const size_t p = (size_t)pbase + it*16 + col;
    const float x0 = xg[p];
    const float x1 = xg[MPTS+p];
    const float x2 = xg[2ul*MPTS+p];
    const float x3 = xg[3ul*MPTS+p];
    const float x4 = xg[4ul*MPTS+p];
    const float x5 = xg[5ul*MPTS+p];

    f32x4 acc0 = {0,0,0,0}, acc1 = {0,0,0,0}, acc2 = {0,0,0,0}, acc3 = {0,0,0,0};

    #pragma unroll
    for (int kt=0; kt<2; ++kt){
      float h[8];
      #pragma unroll
      for (int j=0;j<8;j++){
        float y = cb[kt][j];
        y = fmaf(cw0[kt][j],x0,y); y = fmaf(cw1[kt][j],x1,y);
        y = fmaf(cw2[kt][j],x2,y); y = fmaf(cw3[kt][j],x3,y);
        y = fmaf(cw4[kt][j],x4,y); y = fmaf(cw5[kt][j],x5,y);
        h[j] = fmaxf(y, 0.f);
      }
      uintx4 pk;
      pk[0] = rne_bf16(h[0]) | (rne_bf16(h[1])<<16);
      pk[1] = rne_bf16(h[2]) | (rne_bf16(h[3])<<16);
      pk[2] = rne_bf16(h[4]) | (rne_bf16(h[5])<<16);
      pk[3] = rne_bf16(h[6]) | (rne_bf16(h[7])<<16);
      bf16x8 bfrag = __builtin_bit_cast(bf16x8, pk);
      {
        uintx4 au = *reinterpret_cast<const uintx4*>(&sA1[((0*2+kt)*64+lane)*8]);
        acc0 = __builtin_amdgcn_mfma_f32_16x16x32_bf16(__builtin_bit_cast(bf16x8,au), bfrag, acc0, 0,0,0);
      }
      {
        uintx4 au = *reinterpret_cast<const uintx4*>(&sA1[((1*2+kt)*64+lane)*8]);
        acc1 = __builtin_amdgcn_mfma_f32_16x16x32_bf16(__builtin_bit_cast(bf16x8,au), bfrag, acc1, 0,0,0);
      }
      {
        uintx4 au = *reinterpret_cast<const uintx4*>(&sA1[((2*2+kt)*64+lane)*8]);
        acc2 = __builtin_amdgcn_mfma_f32_16x16x32_bf16(__builtin_bit_cast(bf16x8,au), bfrag, acc2, 0,0,0);
      }
      {
        uintx4 au = *reinterpret_cast<const uintx4*>(&sA1[((3*2+kt)*64+lane)*8]);
        acc3 = __builtin_amdgcn_mfma_f32_16x16x32_bf16(__builtin_bit_cast(bf16x8,au), bfrag, acc3, 0,0,0);
      }
    }
    // epilogue: +b1, stats, pack 4 consecutive o -> uint2, store point-major
    #pragma unroll
    for (int mt=0;mt<4;mt++){
      f32x4 a = (mt==0)?acc0:(mt==1)?acc1:(mt==2)?acc2:acc3;
      float v0 = a[0] + b1v[mt][0];
      float v1 = a[1] + b1v[mt][1];
      float v2 = a[2] + b1v[mt][2];
      float v3 = a[3] + b1v[mt][3];
      s1s[mt][0]+=v0; s1q[mt][0]=fmaf(v0,v0,s1q[mt][0]);
      s1s[mt][1]+=v1; s1q[mt][1]=fmaf(v1,v1,s1q[mt][1]);
      s1s[mt][2]+=v2; s1q[mt][2]=fmaf(v2,v2,s1q[mt][2]);
      s1s[mt][3]+=v3; s1q[mt][3]=fmaf(v3,v3,s1q[mt][3]);
      uint2 st;
      st.x = rne_bf16(v0) | (rne_bf16(v1)<<16);
      st.y = rne_bf16(v2) | (rne_bf16(v3)<<16);
      *reinterpret_cast<uint2*>(y1 + p*64 + mt*16 + kg*4) = st;
    }
  }

  // stats: reduce over the 16 col-lanes (bits 0..3 of lane)
  #pragma unroll
  for (int mt=0;mt<4;mt++){
    #pragma unroll
    for (int r=0;r<4;r++){
      float s = s1s[mt][r], qv = s1q[mt][r];
      s += __shfl_xor(s,1,64); s += __shfl_xor(s,2,64);
      s += __shfl_xor(s,4,64); s += __shfl_xor(s,8,64);
      qv += __shfl_xor(qv,1,64); qv += __shfl_xor(qv,2,64);
      qv += __shfl_xor(qv,4,64); qv += __shfl_xor(qv,8,64);
      if (col==0){
        atomicAdd(&red[mt*16 + kg*4 + r], s);
        atomicAdd(&red[64 + mt*16 + kg*4 + r], qv);
      }
    }
  }
  __syncthreads();
  if (tid < 64){
    atomicAdd(&ws[OFF_S1SUM+tid], red[tid]);
    atomicAdd(&ws[OFF_S1SQ+tid],  red[64+tid]);
  }
}

// MFMA layer 2 with finalize1 folded into staging (tid<64 computes sc1/sh1).
// C[512K x 128] = relu(bn1(Y1))[512K x 64] * W2[64 x 128] + b2.
// A-frag: m=lane&15 (point), k=(lane>>4)*8+j; D: col=lane&15, row=(lane>>4)*4+r.
__global__ __launch_bounds__(256) void l2_mfma_kernel(
    const float* __restrict__ w2g, const float* __restrict__ b2g,
    const float* __restrict__ g1, const float* __restrict__ t1,
    float* __restrict__ ws)
{
  __shared__ __align__(16) unsigned short sB[8192]; // [nt][kt][lane][j]
  __shared__ float s1c[64], s1h[64];
  __shared__ float red[256];
  const int tid = threadIdx.x;
  for (int idx=tid; idx<8192; idx+=256){
    int nt = idx>>10, kt = (idx>>9)&1, l = (idx>>3)&63, j = idx&7;
    int kch = kt*32 + ((l>>4)<<3) + j;
    int o   = (nt<<4) + (l&15);
    sB[idx] = (unsigned short)rne_bf16(w2g[o*64+kch]);
  }
  if (tid<64){
    // finalize1: BN1 scale/shift from y1 stats
    const float Mf = (float)MPTS;
    float mean = ws[OFF_S1SUM+tid]/Mf;
    float var  = ws[OFF_S1SQ+tid]/Mf - mean*mean;
    float sc = g1[tid]/sqrtf(var+EPSF);
    s1c[tid]=sc; s1h[tid]=t1[tid]-mean*sc;
  }
  red[tid]=0.f;
  __syncthreads();

  const int lane = tid & 63;
  const int w    = tid >> 6;
  const int col  = lane & 15;
  const int kg   = lane >> 4;    // 0..3

  float scv[2][8], shv[2][8];
  #pragma unroll
  for (int kt=0;kt<2;kt++)
    #pragma unroll
    for (int j=0;j<8;j++){
      scv[kt][j] = s1c[kt*32 + kg*8 + j];
      shv[kt][j] = s1h[kt*32 + kg*8 + j];
    }
  float b2v[8];
  #pragma unroll
  for (int nt=0;nt<8;nt++) b2v[nt] = b2g[nt*16 + col];

  const unsigned short* y1 = (const unsigned short*)(ws + OFF_Y1U);
  float* maxb = ws + OFF_MAXB;
  float* minb = ws + OFF_MINB;

  float sumacc[8], sqacc[8];
  #pragma unroll
  for (int nt=0;nt<8;nt++){ sumacc[nt]=0.f; sqacc[nt]=0.f; }

  const int gbase = (blockIdx.x*4 + w)*4;
  for (int it=0; it<4; ++it){
    const int g = gbase + it;
    const size_t p0 = (size_t)g*32;
    bf16x8 aA[2][2];
    #pragma unroll
    for (int mh=0; mh<2; ++mh){
      const unsigned short* arow = y1 + (p0 + mh*16 + col)*64 + kg*8;
      #pragma unroll
      for (int kt=0; kt<2; ++kt){
        uintx4 ua = *reinterpret_cast<const uintx4*>(arow + kt*32);
        float h0 = fmaxf(fmaf(scv[kt][0], __uint_as_float(ua[0]<<16),          shv[kt][0]), 0.f);
        float h1 = fmaxf(fmaf(scv[kt][1], __uint_as_float(ua[0]&0xFFFF0000u), shv[kt][1]), 0.f);
        float h2 = fmaxf(fmaf(scv[kt][2], __uint_as_float(ua[1]<<16),          shv[kt][2]), 0.f);
        float h3 = fmaxf(fmaf(scv[kt][3], __uint_as_float(ua[1]&0xFFFF0000u), shv[kt][3]), 0.f);
        float h4 = fmaxf(fmaf(scv[kt][4], __uint_as_float(ua[2]<<16),          shv[kt][4]), 0.f);
        float h5 = fmaxf(fmaf(scv[kt][5], __uint_as_float(ua[2]&0xFFFF0000u), shv[kt][5]), 0.f);
        float h6 = fmaxf(fmaf(scv[kt][6], __uint_as_float(ua[3]<<16),          shv[kt][6]), 0.f);
        float h7 = fmaxf(fmaf(scv[kt][7], __uint_as_float(ua[3]&0xFFFF0000u), shv[kt][7]), 0.f);
        uintx4 pk;
        pk[0] = rne_bf16(h0) | (rne_bf16(h1)<<16);
        pk[1] = rne_bf16(h2) | (rne_bf16(h3)<<16);
        pk[2] = rne_bf16(h4) | (rne_bf16(h5)<<16);
        pk[3] = rne_bf16(h6) | (rne_bf16(h7)<<16);
        aA[mh][kt] = __builtin_bit_cast(bf16x8, pk);
      }
    }
    f32x4 acc[2][8];
    #pragma unroll
    for (int mh=0;mh<2;mh++)
      #pragma unroll
      for (int nt=0;nt<8;nt++){
        f32x4 z = {b2v[nt], b2v[nt], b2v[nt], b2v[nt]};
        acc[mh][nt] = z;
      }
    #pragma unroll
    for (int nt=0;nt<8;nt++){
      #pragma unroll
      for (int kt=0;kt<2;kt++){
        uintx4 bu = *reinterpret_cast<const uintx4*>(&sB[((nt*2+kt)*64 + lane)*8]);
        bf16x8 bv = __builtin_bit_cast(bf16x8, bu);
        acc[0][nt] = __builtin_amdgcn_mfma_f32_16x16x32_bf16(aA[0][kt], bv, acc[0][nt], 0,0,0);
        acc[1][nt] = __builtin_amdgcn_mfma_f32_16x16x32_bf16(aA[1][kt], bv, acc[1][nt], 0,0,0);
      }
    }
    #pragma unroll
    for (int nt=0;nt<8;nt++){
      f32x4 a0 = acc[0][nt], a1 = acc[1][nt];
      float mx = fmaxf(fmaxf(fmaxf(a0[0],a0[1]),fmaxf(a0[2],a0[3])),
                       fmaxf(fmaxf(a1[0],a1[1]),fmaxf(a1[2],a1[3])));
      float mn = fminf(fminf(fminf(a0[0],a0[1]),fminf(a0[2],a0[3])),
                       fminf(fminf(a1[0],a1[1]),fminf(a1[2],a1[3])));
      mx = fmaxf(mx, __shfl_xor(mx,16,64)); mx = fmaxf(mx, __shfl_xor(mx,32,64));
      mn = fminf(mn, __shfl_xor(mn,16,64)); mn = fminf(mn, __shfl_xor(mn,32,64));
      float s = ((a0[0]+a0[1])+(a0[2]+a0[3])) + ((a1[0]+a1[1])+(a1[2]+a1[3]));
      sumacc[nt] += s;
      float qv = 0.f;
      qv = fmaf(a0[0],a0[0],qv); qv = fmaf(a0[1],a0[1],qv);
      qv = fmaf(a0[2],a0[2],qv); qv = fmaf(a0[3],a0[3],qv);
      qv = fmaf(a1[0],a1[0],qv); qv = fmaf(a1[1],a1[1],qv);
      qv = fmaf(a1[2],a1[2],qv); qv = fmaf(a1[3],a1[3],qv);
      sqacc[nt] += qv;
      if (lane < 16){
        maxb[(size_t)g*128 + nt*16 + lane] = mx;
        minb[(size_t)g*128 + nt*16 + lane] = mn;
      }
    }
  }
  #pragma unroll
  for (int nt=0;nt<8;nt++){
    float s = sumacc[nt]; s += __shfl_xor(s,16,64); s += __shfl_xor(s,32,64);
    float qv = sqacc[nt]; qv += __shfl_xor(qv,16,64); qv += __shfl_xor(qv,32,64);
    if (lane < 16){
      atomicAdd(&red[nt*16+lane], s);
      atomicAdd(&red[128+nt*16+lane], qv);
    }
  }
  __syncthreads();
  atomicAdd(&ws[OFF_S2SUM + tid], red[tid]);
}

__global__ __launch_bounds__(256) void final_out_kernel(
    const float* __restrict__ g2, const float* __restrict__ t2,
    const float* __restrict__ ws, float* __restrict__ out)
{
  const int g = blockIdx.x*256 + threadIdx.x; // B*S*128 threads
  const int o = g & 127;
  const float Mf = (float)MPTS;
  float mean = ws[OFF_S2SUM+o] / Mf;
  float var  = ws[OFF_S2SQ+o] / Mf - mean*mean;
  float sc = g2[o] / sqrtf(var + EPSF);
  float sh = t2[o] - mean*sc;
  float v = (sc > 0.f) ? ws[OFF_MAXB+g] : ws[OFF_MINB+g];
  out[BB*SS*3 + g] = fmaxf(fmaf(sc, v, sh), 0.f);
}

extern "C" void kernel_launch(void* const* d_in, const int* in_sizes, int n_in,
                              void* d_out, int out_size, void* d_ws, size_t ws_size,
                              hipStream_t stream)
{
  const float* xyz = (const float*)d_in[0];
  const float* pts = (const float*)d_in[1];
  const int*   fps = (const int*)d_in[2];
  const float* w0  = (const float*)d_in[3];
  const float* b0  = (const float*)d_in[4];
  const float* g0  = (const float*)d_in[5];
  const float* t0  = (const float*)d_in[6];
  const float* w1  = (const float*)d_in[7];
  const float* b1  = (const float*)d_in[8];
  const float* g1  = (const float*)d_in[9];
  const float* t1  = (const float*)d_in[10];
  const float* w2  = (const float*)d_in[11];
  const float* b2  = (const float*)d_in[12];
  const float* g2  = (const float*)d_in[13];
  const float* t2  = (const float*)d_in[14];
  float* out = (float*)d_out;
  float* ws  = (float*)d_ws;

  hipMemsetAsync((void*)(ws + OFF_ST), 0, 512*sizeof(float), stream);
  prep_kernel<<<320,256,0,stream>>>(xyz, fps, out, ws);
  knn_group_kernel<<<BB*SS,256,0,stream>>>(pts, ws);
  mom2_kernel<<<27*8,256,0,stream>>>(ws);
  finalize0b_kernel<<<1,64,0,stream>>>(w0,b0,g0,t0,ws);
  l1_mfma_kernel<<<512,256,0,stream>>>(w1,b1,ws);
  l2_mfma_kernel<<<1024,256,0,stream>>>(w2,b2,g1,t1,ws);
  final_out_kernel<<<(BB*SS*128)/256,256,0,stream>>>(g2,t2,ws,out);
}